// Round 8
// baseline (540.657 us; speedup 1.0000x reference)
//
#include <hip/hip_runtime.h>

#define SEQ 4096
#define DMODEL 1024
#define DSTATE 64
#define DINNER 2048
#define MROWS 8192            // BATCH*SEQ
#define NCAT 1152             // Bcat rows: 1024 (dt) + 64 (xp) + 64 pad
#define NCHUNK 64             // scan chunks
#define LCHUNK 64             // steps per chunk

typedef __attribute__((ext_vector_type(8))) __bf16 bf16x8;
typedef __attribute__((ext_vector_type(8))) short short8;
typedef __attribute__((ext_vector_type(4))) float floatx4;

__device__ inline float bf2f(short s) {
  union { unsigned u; float f; } c;
  c.u = ((unsigned)(unsigned short)s) << 16;
  return c.f;
}
__device__ inline short f2bf(float f) {
  union { float f; unsigned u; } c; c.f = f;
  unsigned r = 0x7fffu + ((c.u >> 16) & 1u);
  return (short)((c.u + r) >> 16);
}
__device__ inline float silu_f(float v) {
  return v * __builtin_amdgcn_rcpf(1.f + __expf(-v));
}
__device__ inline float softplus_f(float v) {
  return fmaxf(v, 0.f) + log1pf(__expf(-fabsf(v)));
}
// async global->LDS, 16B per lane. LDS dest = wave-uniform base + lane*16.
__device__ inline void gld_lds16(const void* g, void* l) {
  __builtin_amdgcn_global_load_lds(
      (__attribute__((address_space(1))) void*)g,
      (__attribute__((address_space(3))) void*)l, 16, 0, 0);
}

// panel-staged bf16 layout: panel = 16 rows, stored contiguously (K*32 bytes),
// inside: [k-chunk of 8][row-in-panel 16][8 elems].  element (r,k):
__device__ inline size_t permOff(int r, int k, int K) {
  return (((size_t)(r >> 4) * (K >> 3) + (k >> 3)) << 7) + ((r & 15) << 3) + (k & 7);
}

// in_proj column pairing: xi col c -> newrow ((c>>4)<<5)|(c&15);
// g col c (orig 2048+c) -> newrow ((c>>4)<<5)|16|(c&15). Each 32-row block of
// Wt_in = 16 xi cols + their 16 matching g cols -> GEMM1 fragment pair
// (ct even, ct odd) holds xi and g for the SAME phi in the SAME lane.
__device__ inline int inproj_remap(int oc) {
  const int c = (oc < DINNER) ? oc : oc - DINNER;
  return ((c >> 4) << 5) | ((oc < DINNER) ? 0 : 16) | (c & 15);
}

// ---------------- fused pre-pass ---------------------------------------------
#define PP0 4096
#define PP1 (PP0 + 4096)
#define PP2 (PP1 + 2048)
#define PP3 (PP2 + 128)
#define PP4 (PP3 + 2048)

__device__ void tile_transpose_perm(const float* __restrict__ in, short* __restrict__ out,
                                    int R, int C, int bx, int by, float (*tile)[33],
                                    int remap) {
  const int tx = threadIdx.x & 31, ty = threadIdx.x >> 5;   // 32 x 8
  const int cb = bx * 32, rb = by * 32;
#pragma unroll
  for (int i = 0; i < 32; i += 8) {
    int r = rb + ty + i, c = cb + tx;
    tile[ty + i][tx] = (r < R && c < C) ? in[(size_t)r * C + c] : 0.f;
  }
  __syncthreads();
#pragma unroll
  for (int i = 0; i < 32; i += 8) {
    int orow = cb + ty + i, oc = rb + tx;   // out(row=orow, k=oc) = in[oc][orow]
    if (orow < C && oc < R) {
      int nr = remap ? inproj_remap(orow) : orow;
      out[permOff(nr, oc, R)] = f2bf(tile[tx][ty + i]);
    }
  }
}

__global__ void prepass_kernel(const float* __restrict__ x, short* __restrict__ x_bf,
                               const float* __restrict__ W_in, short* __restrict__ Wt_in,
                               const float* __restrict__ W_dt, const float* __restrict__ W_xp,
                               short* __restrict__ Bcat,
                               const float* __restrict__ W_out, short* __restrict__ Wt_out) {
  __shared__ float tile[32][33];
  const int blk = blockIdx.x;
  if (blk < PP0) {
    int o = blk * 256 + threadIdx.x;            // [0, 1M) 16B groups
    int m = o & 15, rest = o >> 4;
    int c = rest & 127, p = rest >> 7;          // K/8 = 128 chunks
    const float* src = x + ((size_t)(p * 16 + m)) * 1024 + c * 8;
    float4 v0 = ((const float4*)src)[0];
    float4 v1 = ((const float4*)src)[1];
    short8 ov;
    ov[0] = f2bf(v0.x); ov[1] = f2bf(v0.y); ov[2] = f2bf(v0.z); ov[3] = f2bf(v0.w);
    ov[4] = f2bf(v1.x); ov[5] = f2bf(v1.y); ov[6] = f2bf(v1.z); ov[7] = f2bf(v1.w);
    ((short8*)x_bf)[o] = ov;
  } else if (blk < PP1) {
    int t = blk - PP0;
    tile_transpose_perm(W_in, Wt_in, 1024, 4096, t & 127, t >> 7, tile, 1);
  } else if (blk < PP2) {
    int t = blk - PP1;
    tile_transpose_perm(W_dt, Bcat, 2048, 1024, t & 31, t >> 5, tile, 0);
  } else if (blk < PP3) {
    int t = blk - PP2;
    tile_transpose_perm(W_xp, Bcat + (size_t)1024 * DINNER, 2048, 64, t & 1, t >> 1, tile, 0);
  } else {
    int t = blk - PP3;
    tile_transpose_perm(W_out, Wt_out, 2048, 1024, t & 31, t >> 5, tile, 0);
  }
}

// ---------------- 256x256 read-ahead bf16 GEMM (counted-lgkm pipeline) -------
// R5-verified schedule (80.4us/36% on GEMM1). 512 thr = 8 waves (2M x 4N);
// wave owns 128x64 = 8x4 frags. BK=64, 2 LDS buffers x 64KB = 128KB.
// Read group for MFMA cluster k+1 issued BEFORE cluster k's MFMAs -> compiler
// emits counted lgkmcnt; LDS port overlaps matrix pipe. Two barriers/tile,
// counted vmcnt(4) twice/tile; never drains mid-loop. (Ledger in R5 notes.)
// MODE 0: paired in_proj epilogue (remapped Wt_in): even ct frag = xi col phi,
//   odd ct frag = g col phi (same lane). Writes xi=silu(.) to out0 and
//   prod=silu(xi)*silu(g) to out1 (panel-staged). s_sum applied downstream.
template <int MODE, int KTOT, int KSL, int NT, int ZS>
__global__ __launch_bounds__(512, 2) void gemm256(
    const short* __restrict__ A, const short* __restrict__ Bt,
    const float* __restrict__ bias,
    void* __restrict__ out0, void* __restrict__ out1)
{
  __shared__ __attribute__((aligned(16))) short sLds[65536];   // 128 KiB

  const int tid = threadIdx.x;
  const int lane = tid & 63;
  const int w = tid >> 6;              // 0..7
  const int wr = w >> 2, wc = w & 3;   // 2 x 4 wave grid
  const int m = lane & 15, quad = lane >> 4;

  const int xcd = blockIdx.x & 7;
  const int q = blockIdx.x >> 3;
  const int mt = xcd * 4 + (q & 3);
  const int rest = q >> 2;
  const int ntile = rest % NT;
  const int z = rest / NT;
  const int bM = mt * 256, bN = ntile * 256;
  const int kbeg = z * KSL;

  floatx4 acc[8][4] = {};

  const size_t PS = (size_t)KTOT * 16;   // panel stride in shorts
  const short* AgA = A  + ((size_t)(bM >> 4) + w) * PS + (size_t)kbeg * 16 + lane * 8;
  const short* AgB = AgA + 8 * PS;
  const short* BgA = Bt + ((size_t)(bN >> 4) + w) * PS + (size_t)kbeg * 16 + lane * 8;
  const short* BgB = BgA + 8 * PS;

  constexpr int KT = KSL / 64;           // K-tiles of 64 (>= 2)

  auto STAGE_Q = [&](int t, int qq) {    // quarter qq: 0:A-kh0 1:B-kh0 2:A-kh1 3:B-kh1
    const size_t go = (size_t)t * 1024 + (size_t)(qq >> 1) * 512;
    short* d = sLds + ((t & 1) << 15) + ((qq & 1) << 14) + ((qq >> 1) << 13) + w * 512;
    const short* g0 = (qq & 1) ? BgA : AgA;   // panel w
    const short* g1 = (qq & 1) ? BgB : AgB;   // panel w+8
    gld_lds16(g0 + go, d);
    gld_lds16(g1 + go, d + 4096);
  };

  const int aoff = wr * 4096 + quad * 128 + m * 8;           // + rt*512 + kh*8192
  const int boff = 16384 + wc * 2048 + quad * 128 + m * 8;   // + ct*512 + kh*8192

  bf16x8 aA[4], aB[4], bA[4], bB[4];

  STAGE_Q(0, 0); STAGE_Q(0, 1); STAGE_Q(0, 2); STAGE_Q(0, 3);
  asm volatile("s_waitcnt vmcnt(4)" ::: "memory");
  asm volatile("s_barrier" ::: "memory");
  {
    const short* bs = sLds;
#pragma unroll
    for (int rt = 0; rt < 4; ++rt) aA[rt] = *(const bf16x8*)(bs + aoff + rt * 512);
#pragma unroll
    for (int ct = 0; ct < 4; ++ct) bA[ct] = *(const bf16x8*)(bs + boff + ct * 512);
    if (KT > 1) STAGE_Q(1, 0);
    __builtin_amdgcn_sched_barrier(0);
  }

#pragma unroll 1
  for (int t = 0; t < KT; ++t) {
    const short* bs = sLds + ((t & 1) << 15);
    const bool pf = (t + 1 < KT);

#pragma unroll
    for (int rt = 0; rt < 4; ++rt) aB[rt] = *(const bf16x8*)(bs + aoff + (4 + rt) * 512);
    if (pf) {
      STAGE_Q(t + 1, 1);
      asm volatile("s_waitcnt vmcnt(4)" ::: "memory");
    } else {
      asm volatile("s_waitcnt vmcnt(0)" ::: "memory");
    }
    __builtin_amdgcn_sched_barrier(0);
    __builtin_amdgcn_s_setprio(1);
#pragma unroll
    for (int rt = 0; rt < 4; ++rt)
#pragma unroll
      for (int ct = 0; ct < 4; ++ct)
        acc[rt][ct] = __builtin_amdgcn_mfma_f32_16x16x32_bf16(aA[rt], bA[ct], acc[rt][ct], 0, 0, 0);
    __builtin_amdgcn_s_setprio(0);
    __builtin_amdgcn_sched_barrier(0);

    asm volatile("s_waitcnt lgkmcnt(0)" ::: "memory");
    asm volatile("s_barrier" ::: "memory");
#pragma unroll
    for (int rt = 0; rt < 4; ++rt) aA[rt] = *(const bf16x8*)(bs + 8192 + aoff + rt * 512);
#pragma unroll
    for (int ct = 0; ct < 4; ++ct) bB[ct] = *(const bf16x8*)(bs + 8192 + boff + ct * 512);
    if (pf) STAGE_Q(t + 1, 2);
    __builtin_amdgcn_sched_barrier(0);
    __builtin_amdgcn_s_setprio(1);
#pragma unroll
    for (int rt = 0; rt < 4; ++rt)
#pragma unroll
      for (int ct = 0; ct < 4; ++ct)
        acc[4 + rt][ct] = __builtin_amdgcn_mfma_f32_16x16x32_bf16(aB[rt], bA[ct], acc[4 + rt][ct], 0, 0, 0);
    __builtin_amdgcn_s_setprio(0);
    __builtin_amdgcn_sched_barrier(0);

#pragma unroll
    for (int rt = 0; rt < 4; ++rt) aB[rt] = *(const bf16x8*)(bs + 8192 + aoff + (4 + rt) * 512);
    if (pf) {
      STAGE_Q(t + 1, 3);
      asm volatile("s_waitcnt vmcnt(4)" ::: "memory");
    }
    __builtin_amdgcn_sched_barrier(0);
    __builtin_amdgcn_s_setprio(1);
#pragma unroll
    for (int rt = 0; rt < 4; ++rt)
#pragma unroll
      for (int ct = 0; ct < 4; ++ct)
        acc[rt][ct] = __builtin_amdgcn_mfma_f32_16x16x32_bf16(aA[rt], bB[ct], acc[rt][ct], 0, 0, 0);
    __builtin_amdgcn_s_setprio(0);
    __builtin_amdgcn_sched_barrier(0);

    if (pf) {
      asm volatile("s_waitcnt lgkmcnt(0)" ::: "memory");
      asm volatile("s_barrier" ::: "memory");
      const short* bs2 = sLds + (((t + 1) & 1) << 15);
#pragma unroll
      for (int rt = 0; rt < 4; ++rt) aA[rt] = *(const bf16x8*)(bs2 + aoff + rt * 512);
#pragma unroll
      for (int ct = 0; ct < 4; ++ct) bA[ct] = *(const bf16x8*)(bs2 + boff + ct * 512);
      if (t + 2 < KT) STAGE_Q(t + 2, 0);
      __builtin_amdgcn_sched_barrier(0);
    }
    __builtin_amdgcn_s_setprio(1);
#pragma unroll
    for (int rt = 0; rt < 4; ++rt)
#pragma unroll
      for (int ct = 0; ct < 4; ++ct)
        acc[4 + rt][ct] = __builtin_amdgcn_mfma_f32_16x16x32_bf16(aB[rt], bB[ct], acc[4 + rt][ct], 0, 0, 0);
    __builtin_amdgcn_s_setprio(0);
    __builtin_amdgcn_sched_barrier(0);
  }

  const int rowbase = bM + wr * 128;
  const int colbase = bN + wc * 64;

  if constexpr (MODE == 0) {
    // paired in_proj epilogue: even/odd ct frags = xi/g at the same phi.
    short* xid = (short*)out0;
    short* prd = (short*)out1;
#pragma unroll
    for (int cp = 0; cp < 2; ++cp) {
      const int newcolE = colbase + cp * 32 + m;
      const int phi = ((newcolE >> 5) << 4) | (newcolE & 15);   // 0..2047
      const float bxi = bias[phi];
      const float bg  = bias[DINNER + phi];
#pragma unroll
      for (int rt = 0; rt < 8; ++rt) {
        const size_t rowPan = ((size_t)(rowbase >> 4) + rt) << 8;
        const size_t base = ((rowPan + (phi >> 3)) << 7) + (phi & 7) + ((size_t)quad * 32);
#pragma unroll
        for (int reg = 0; reg < 4; ++reg) {
          const float xv = silu_f(acc[rt][2 * cp][reg] + bxi);
          const float gv = silu_f(acc[rt][2 * cp + 1][reg] + bg);
          xid[base + reg * 8] = f2bf(xv);
          prd[base + reg * 8] = f2bf(xv * gv);
        }
      }
    }
  } else {
    constexpr int N = NT * 256;
    short* dst = (short*)out0 + (size_t)z * MROWS * N;
#pragma unroll
    for (int rt = 0; rt < 8; ++rt)
#pragma unroll
      for (int ct = 0; ct < 4; ++ct) {
        const int col = colbase + ct * 16 + m;
#pragma unroll
        for (int reg = 0; reg < 4; ++reg) {
          const int r = rowbase + rt * 16 + quad * 4 + reg;
          dst[(size_t)r * N + col] = f2bf(acc[rt][ct][reg]);
        }
      }
  }
}

// ---------------- 256x128 full-K bf16 GEMM with fused epilogues --------------
// Same R5 read-ahead/counted-waitcnt skeleton, 4 waves (2M x 2N), wave owns
// 128x64 = identical acc[8][4] and read groups G0(8)/G1(4)/G2(8)/G3(4).
// Full K=2048 (KT=32) -> no split-K partials; grid = 32 Mt x 8 Nt = 256
// blocks (machine full). LDS: 2 buf x (A 16 panels + B 8 panels) x 2kh x
// 512sh = 2 x 24576 shorts = 96KB -> 1 block/CU, 1 wave/SIMD.
// Staging per wave per K-tile: Q0=A-kh0(4 glds: panels w+4j), Q1=B-kh0(2),
// Q2=A-kh1(4), Q3=B-kh1(2) = 12. Ledger: at phB(t) after STAGE Q(t+1,1):
// outstanding = Q(t,2)4+Q(t,3)2+Q(t+1,0)4+Q(t+1,1)2 = 12 -> vmcnt(6) retires
// Q(t,2),Q(t,3) (needed by phC). At phD(t) after Q(t+1,3): outstanding =
// Q(t+1,0..3) = 12 -> vmcnt(6) retires Q(t+1,0),Q(t+1,1) (needed by phA(t+1)).
// Prologue: 12 staged, vmcnt(6) -> Q(0,0),Q(0,1) landed. Tail vmcnt(0).
// WAR: lgkmcnt(0)+s_barrier precede every opposite-buffer stage (as R5).
// MODE 2 (dt): softplus(acc+b_dt) rowsum over wave's 64 cols via 16-lane
//   shfl_xor reduce -> fp32 atomicAdd into md_sum (zeroed by memset).
// MODE 3 (out_proj): out = s_sum[r]*acc + b_out[c] + x[r][c]*D[c], direct.
template <int MODE>
__global__ __launch_bounds__(256) void gemm128(
    const short* __restrict__ A, const short* __restrict__ Bt,
    const float* __restrict__ bvec, const float* __restrict__ xin,
    const float* __restrict__ Dv, const float* __restrict__ s_sum,
    float* __restrict__ out)
{
  __shared__ __attribute__((aligned(16))) short sLds[49152];   // 96 KiB

  const int tid = threadIdx.x;
  const int lane = tid & 63;
  const int w = tid >> 6;              // 0..3
  const int wr = w >> 1, wc = w & 1;   // 2 x 2 wave grid
  const int m = lane & 15, quad = lane >> 4;

  // XCD-aware grid: 32 M-tiles x 8 N-tiles
  const int xcd = blockIdx.x & 7;
  const int q = blockIdx.x >> 3;
  const int mt = xcd * 4 + (q & 3);
  const int ntile = q >> 2;            // 0..7
  const int bM = mt * 256, bN = ntile * 128;

  floatx4 acc[8][4] = {};

  const size_t PS = (size_t)2048 * 16;   // panel stride in shorts (K=2048)
  const short* Ag = A  + ((size_t)(bM >> 4) + w) * PS + lane * 8;   // +4j*PS
  const short* Bg = Bt + ((size_t)(bN >> 4) + w) * PS + lane * 8;   // +4j*PS
  constexpr int KT = 32;

  // LDS map (shorts): buf(t&1)*24576 + {A: kh*8192 + panel*512 (16 panels);
  //                                     B: 16384 + kh*4096 + panel*512 (8)}
  auto STAGE_Q = [&](int t, int qq) {    // 0:A-kh0 1:B-kh0 2:A-kh1 3:B-kh1
    const size_t go = (size_t)t * 1024 + (size_t)(qq >> 1) * 512;
    if ((qq & 1) == 0) {                 // A quarter: panels w+4j, j=0..3
      short* d = sLds + (t & 1) * 24576 + (qq >> 1) * 8192 + w * 512;
#pragma unroll
      for (int j = 0; j < 4; ++j) gld_lds16(Ag + (size_t)j * 4 * PS + go, d + j * 2048);
    } else {                             // B quarter: panels w+4j, j=0..1
      short* d = sLds + (t & 1) * 24576 + 16384 + (qq >> 1) * 4096 + w * 512;
#pragma unroll
      for (int j = 0; j < 2; ++j) gld_lds16(Bg + (size_t)j * 4 * PS + go, d + j * 2048);
    }
  };

  const int aoff = wr * 4096 + quad * 128 + m * 8;           // + rt*512 (+8192 kh1)
  const int boff = 16384 + wc * 2048 + quad * 128 + m * 8;   // + ct*512 (+4096 kh1)

  bf16x8 aA[4], aB[4], bA[4], bB[4];

  STAGE_Q(0, 0); STAGE_Q(0, 1); STAGE_Q(0, 2); STAGE_Q(0, 3);
  asm volatile("s_waitcnt vmcnt(6)" ::: "memory");   // Q(0,0),Q(0,1) landed (mine)
  asm volatile("s_barrier" ::: "memory");
  {
    const short* bs = sLds;
#pragma unroll
    for (int rt = 0; rt < 4; ++rt) aA[rt] = *(const bf16x8*)(bs + aoff + rt * 512);
#pragma unroll
    for (int ct = 0; ct < 4; ++ct) bA[ct] = *(const bf16x8*)(bs + boff + ct * 512);
    STAGE_Q(1, 0);
    __builtin_amdgcn_sched_barrier(0);
  }

#pragma unroll 1
  for (int t = 0; t < KT; ++t) {
    const short* bs = sLds + (t & 1) * 24576;
    const bool pf = (t + 1 < KT);

    // ---- phase B: G1 | stage Q(t+1,1) | vmcnt(6) | M0
#pragma unroll
    for (int rt = 0; rt < 4; ++rt) aB[rt] = *(const bf16x8*)(bs + aoff + (4 + rt) * 512);
    if (pf) {
      STAGE_Q(t + 1, 1);
      asm volatile("s_waitcnt vmcnt(6)" ::: "memory");   // Q(t,2),Q(t,3) landed
    } else {
      asm volatile("s_waitcnt vmcnt(0)" ::: "memory");
    }
    __builtin_amdgcn_sched_barrier(0);
    __builtin_amdgcn_s_setprio(1);
#pragma unroll
    for (int rt = 0; rt < 4; ++rt)
#pragma unroll
      for (int ct = 0; ct < 4; ++ct)
        acc[rt][ct] = __builtin_amdgcn_mfma_f32_16x16x32_bf16(aA[rt], bA[ct], acc[rt][ct], 0, 0, 0);
    __builtin_amdgcn_s_setprio(0);
    __builtin_amdgcn_sched_barrier(0);

    // ---- phase C: lgkm0 + barrier | G2 | stage Q(t+1,2) | M1
    asm volatile("s_waitcnt lgkmcnt(0)" ::: "memory");
    asm volatile("s_barrier" ::: "memory");              // kh1 landed globally
#pragma unroll
    for (int rt = 0; rt < 4; ++rt) aA[rt] = *(const bf16x8*)(bs + 8192 + aoff + rt * 512);
#pragma unroll
    for (int ct = 0; ct < 4; ++ct) bB[ct] = *(const bf16x8*)(bs + 4096 + boff + ct * 512);
    if (pf) STAGE_Q(t + 1, 2);
    __builtin_amdgcn_sched_barrier(0);
    __builtin_amdgcn_s_setprio(1);
#pragma unroll
    for (int rt = 0; rt < 4; ++rt)
#pragma unroll
      for (int ct = 0; ct < 4; ++ct)
        acc[4 + rt][ct] = __builtin_amdgcn_mfma_f32_16x16x32_bf16(aB[rt], bA[ct], acc[4 + rt][ct], 0, 0, 0);
    __builtin_amdgcn_s_setprio(0);
    __builtin_amdgcn_sched_barrier(0);

    // ---- phase D: G3 | stage Q(t+1,3) | vmcnt(6) | M2
#pragma unroll
    for (int rt = 0; rt < 4; ++rt) aB[rt] = *(const bf16x8*)(bs + 8192 + aoff + (4 + rt) * 512);
    if (pf) {
      STAGE_Q(t + 1, 3);
      asm volatile("s_waitcnt vmcnt(6)" ::: "memory");   // Q(t+1,0),Q(t+1,1) landed
    }
    __builtin_amdgcn_sched_barrier(0);
    __builtin_amdgcn_s_setprio(1);
#pragma unroll
    for (int rt = 0; rt < 4; ++rt)
#pragma unroll
      for (int ct = 0; ct < 4; ++ct)
        acc[rt][ct] = __builtin_amdgcn_mfma_f32_16x16x32_bf16(aA[rt], bB[ct], acc[rt][ct], 0, 0, 0);
    __builtin_amdgcn_s_setprio(0);
    __builtin_amdgcn_sched_barrier(0);

    // ---- phase A(t+1): lgkm0 + barrier | G0(t+1) | stage Q(t+2,0)
    if (pf) {
      asm volatile("s_waitcnt lgkmcnt(0)" ::: "memory"); // WAR-safe
      asm volatile("s_barrier" ::: "memory");
      const short* bs2 = sLds + ((t + 1) & 1) * 24576;
#pragma unroll
      for (int rt = 0; rt < 4; ++rt) aA[rt] = *(const bf16x8*)(bs2 + aoff + rt * 512);
#pragma unroll
      for (int ct = 0; ct < 4; ++ct) bA[ct] = *(const bf16x8*)(bs2 + boff + ct * 512);
      if (t + 2 < KT) STAGE_Q(t + 2, 0);
      __builtin_amdgcn_sched_barrier(0);
    }
    // ---- M3
    __builtin_amdgcn_s_setprio(1);
#pragma unroll
    for (int rt = 0; rt < 4; ++rt)
#pragma unroll
      for (int ct = 0; ct < 4; ++ct)
        acc[4 + rt][ct] = __builtin_amdgcn_mfma_f32_16x16x32_bf16(aB[rt], bB[ct], acc[4 + rt][ct], 0, 0, 0);
    __builtin_amdgcn_s_setprio(0);
    __builtin_amdgcn_sched_barrier(0);
  }

  const int rowbase = bM + wr * 128;
  const int colbase = bN + wc * 64;

  if constexpr (MODE == 2) {
    // softplus rowsum over this wave's 64 cols -> atomicAdd md_sum[row]
    float bd[4];
#pragma unroll
    for (int ct = 0; ct < 4; ++ct) bd[ct] = bvec[colbase + ct * 16 + m];
#pragma unroll
    for (int rt = 0; rt < 8; ++rt)
#pragma unroll
      for (int reg = 0; reg < 4; ++reg) {
        float s = 0.f;
#pragma unroll
        for (int ct = 0; ct < 4; ++ct) s += softplus_f(acc[rt][ct][reg] + bd[ct]);
        s += __shfl_xor(s, 1); s += __shfl_xor(s, 2);
        s += __shfl_xor(s, 4); s += __shfl_xor(s, 8);
        if (m == 0) atomicAdd(out + rowbase + rt * 16 + quad * 4 + reg, s);
      }
  } else {
    // out = s_sum[r]*acc + b_out[c] + x[r][c]*D[c]  (full-K, each elem once)
    float bo[4], dv[4];
#pragma unroll
    for (int ct = 0; ct < 4; ++ct) {
      bo[ct] = bvec[colbase + ct * 16 + m];
      dv[ct] = Dv[colbase + ct * 16 + m];
    }
#pragma unroll
    for (int rt = 0; rt < 8; ++rt)
#pragma unroll
      for (int reg = 0; reg < 4; ++reg) {
        const int r = rowbase + rt * 16 + quad * 4 + reg;
        const float s = s_sum[r];
#pragma unroll
        for (int ct = 0; ct < 4; ++ct) {
          const size_t o = (size_t)r * DMODEL + colbase + ct * 16 + m;
          out[o] = s * acc[rt][ct][reg] + bo[ct] + xin[o] * dv[ct];
        }
      }
  }
}

// ---------------- skinny xp GEMM: bx partials = xi @ W_xp (fp32) -------------
__global__ __launch_bounds__(256) void xp_gemm(const short* __restrict__ xi,
                                               const short* __restrict__ Bxp,
                                               float* __restrict__ bxp) {
  __shared__ __attribute__((aligned(16))) short sA[2][4096];
  __shared__ __attribute__((aligned(16))) short sB[2][4096];
  const int tid = threadIdx.x, lane = tid & 63, w = tid >> 6;
  const int m = lane & 15, quad = lane >> 4;
  const int z = blockIdx.x >> 7;            // K-slice
  const int rb = (blockIdx.x & 127) * 64;   // row base
  const size_t PS = (size_t)2048 * 16;      // panel stride (shorts)
  const short* Ag = xi  + ((size_t)(rb >> 4) + w) * PS + (size_t)z * 1024 * 16 + lane * 8;
  const short* Bg = Bxp + (size_t)w * PS + (size_t)z * 1024 * 16 + lane * 8;
  floatx4 acc[4] = {};
  auto STAGE = [&](int t) {                 // 4 gld_lds per wave
    const size_t go = (size_t)t * 1024;
    short* da = sA[t & 1] + w * 1024;
    short* db = sB[t & 1] + w * 1024;
    gld_lds16(Ag + go, da); gld_lds16(Ag + go + 512, da + 512);
    gld_lds16(Bg + go, db); gld_lds16(Bg + go + 512, db + 512);
  };
  STAGE(0);
#pragma unroll 1
  for (int t = 0; t < 16; ++t) {
    __builtin_amdgcn_s_barrier();
    if (t + 1 < 16) {
      STAGE(t + 1);
      asm volatile("s_waitcnt vmcnt(4)" ::: "memory");
    } else {
      asm volatile("s_waitcnt vmcnt(0)" ::: "memory");
    }
    __builtin_amdgcn_s_barrier();
    const short* a0 = sA[t & 1] + w * 1024 + quad * 128 + m * 8;
    const short* b0 = sB[t & 1] + quad * 128 + m * 8;
#pragma unroll
    for (int kh = 0; kh < 2; ++kh) {
      bf16x8 a = *(const bf16x8*)(a0 + kh * 512);
#pragma unroll
      for (int ct = 0; ct < 4; ++ct) {
        bf16x8 b = *(const bf16x8*)(b0 + ct * 1024 + kh * 512);
        acc[ct] = __builtin_amdgcn_mfma_f32_16x16x32_bf16(a, b, acc[ct], 0, 0, 0);
      }
    }
  }
  float* dst = bxp + (size_t)z * MROWS * DSTATE;
#pragma unroll
  for (int ct = 0; ct < 4; ++ct)
#pragma unroll
    for (int reg = 0; reg < 4; ++reg)
      dst[(size_t)(rb + w * 16 + quad * 4 + reg) * DSTATE + ct * 16 + m] = acc[ct][reg];
}

// ---------------- chunked selective scan (2 phases) --------------------------
// bx value = bxp[0][row][n] + bxp[1][row][n] + b_xp[n] (fp32 split-K partials)
__global__ void scan_phase1(const float* __restrict__ md_sum, const float* __restrict__ A_log,
                            const float* __restrict__ bxp, const float* __restrict__ b_xp,
                            float* __restrict__ chunk_prod, float* __restrict__ chunk_end) {
  const int n = threadIdx.x;                // 0..63 (state dim)
  const int c = blockIdx.x & (NCHUNK - 1);  // chunk
  const int b = blockIdx.x >> 6;            // batch
  const float An = -__expf(A_log[n]);
  const float bxn = b_xp[n];
  const float* bx0 = bxp;
  const float* bx1 = bxp + (size_t)MROWS * DSTATE;
  float prod = 1.f, st = 0.f;
  const int t0 = c * LCHUNK;
#pragma unroll 4
  for (int i = 0; i < LCHUNK; ++i) {
    const int t = t0 + i;
    const float md = md_sum[b * SEQ + t] * (1.f / DMODEL);
    const float a = __expf(An * md);
    const size_t idx = ((size_t)(b * SEQ + t)) * DSTATE + n;
    st = a * st + (bx0[idx] + bx1[idx] + bxn);
    prod *= a;
  }
  chunk_prod[(b * NCHUNK + c) * DSTATE + n] = prod;
  chunk_end [(b * NCHUNK + c) * DSTATE + n] = st;
}

// phase3: redo own chunk-prefix, recompute a=exp(An*md), emit s_sum
__global__ void scan_phase3(const float* __restrict__ md_sum, const float* __restrict__ A_log,
                            const float* __restrict__ bxp, const float* __restrict__ b_xp,
                            const float* __restrict__ chunk_prod,
                            const float* __restrict__ chunk_end,
                            float* __restrict__ s_sum) {
  const int n = threadIdx.x;
  const int c = blockIdx.x & (NCHUNK - 1);
  const int b = blockIdx.x >> 6;
  const float An = -__expf(A_log[n]);
  const float bxn = b_xp[n];
  const float* bx0 = bxp;
  const float* bx1 = bxp + (size_t)MROWS * DSTATE;
  float st = 0.f;
#pragma unroll 4
  for (int cc = 0; cc < c; ++cc) {
    const size_t idx = ((size_t)(b * NCHUNK + cc)) * DSTATE + n;
    st = chunk_prod[idx] * st + chunk_end[idx];
  }
  const int t0 = c * LCHUNK;
#pragma unroll 4
  for (int i = 0; i < LCHUNK; ++i) {
    const int t = t0 + i;
    const float md = md_sum[b * SEQ + t] * (1.f / DMODEL);
    const float a = __expf(An * md);
    const size_t idx = ((size_t)(b * SEQ + t)) * DSTATE + n;
    st = a * st + (bx0[idx] + bx1[idx] + bxn);
    float v = st;
    v += __shfl_xor(v, 32); v += __shfl_xor(v, 16); v += __shfl_xor(v, 8);
    v += __shfl_xor(v, 4);  v += __shfl_xor(v, 2);  v += __shfl_xor(v, 1);
    if (n == 0) s_sum[b * SEQ + t] = v;
  }
}

// ---------------- launch ------------------------------------------------------
extern "C" void kernel_launch(void* const* d_in, const int* in_sizes, int n_in,
                              void* d_out, int out_size, void* d_ws, size_t ws_size,
                              hipStream_t stream) {
  const float* x     = (const float*)d_in[0];
  const float* W_in  = (const float*)d_in[1];
  const float* b_in  = (const float*)d_in[2];
  const float* W_xp  = (const float*)d_in[3];
  const float* b_xp  = (const float*)d_in[4];
  const float* W_dt  = (const float*)d_in[5];
  const float* b_dt  = (const float*)d_in[6];
  const float* W_out = (const float*)d_in[7];
  const float* b_out = (const float*)d_in[8];
  const float* A_log = (const float*)d_in[9];
  const float* Dv    = (const float*)d_in[10];

  char* ws = (char*)d_ws;
  size_t off = 0;
  auto alloc = [&](size_t bytes) -> void* {
    void* p = (void*)(ws + off);
    off += (bytes + 255) & ~(size_t)255;
    return p;
  };
  short* x_bf    = (short*)alloc((size_t)MROWS * DMODEL * 2);
  short* Wt_in   = (short*)alloc((size_t)4096 * 1024 * 2);
  short* Bcat    = (short*)alloc((size_t)NCAT * DINNER * 2);
  short* Wt_out  = (short*)alloc((size_t)1024 * 2048 * 2);
  short* xi      = (short*)alloc((size_t)MROWS * DINNER * 2);
  short* prod    = (short*)alloc((size_t)MROWS * DINNER * 2);   // silu(xi)*silu(g)
  float* md_sum  = (float*)alloc((size_t)MROWS * 4);
  float* bxp     = (float*)alloc((size_t)2 * MROWS * DSTATE * 4); // xp partials
  float* cprod   = (float*)alloc((size_t)2 * NCHUNK * DSTATE * 4);
  float* cend    = (float*)alloc((size_t)2 * NCHUNK * DSTATE * 4);
  float* s_sum   = (float*)alloc((size_t)MROWS * 4);

  // md_sum accumulated via fp32 atomics in gemm128<2> -> zero it first
  hipMemsetAsync(md_sum, 0, (size_t)MROWS * 4, stream);

  // fused pre-pass: x->bf16 (panel-staged) + all 4 weight transposes
  prepass_kernel<<<PP4, 256, 0, stream>>>(x, x_bf, W_in, Wt_in, W_dt, W_xp, Bcat, W_out, Wt_out);

  // GEMM1: in_proj, paired epilogue -> xi + prod (ymul folded in)
  gemm256<0, 1024, 1024, 16, 1><<<512, 512, 0, stream>>>(x_bf, Wt_in, b_in, xi, prod);
  // GEMM2-dt: full-K 256x128, fused softplus-rowsum -> md_sum (atomics)
  gemm128<2><<<256, 256, 0, stream>>>(xi, Bcat, b_dt, nullptr, nullptr, nullptr, md_sum);
  // GEMM2-xp: skinny N=64, fp32 partials straight into bxp
  xp_gemm<<<256, 256, 0, stream>>>(xi, Bcat + (size_t)1024 * DINNER, bxp);
  // selective scan (phase3 self-computes its chunk prefix)
  scan_phase1<<<2 * NCHUNK, DSTATE, 0, stream>>>(md_sum, A_log, bxp, b_xp, cprod, cend);
  scan_phase3<<<2 * NCHUNK, DSTATE, 0, stream>>>(md_sum, A_log, bxp, b_xp, cprod, cend, s_sum);
  // GEMM4: full-K 256x128, fused epilogue (s_sum scale + b_out + x*D) -> out
  gemm128<3><<<256, 256, 0, stream>>>(prod, Wt_out, b_out, x, Dv, s_sum, (float*)d_out);
}

// Round 9
// 361.644 us; speedup vs baseline: 1.4950x; 1.4950x over previous
//
#include <hip/hip_runtime.h>

#define SEQ 4096
#define DMODEL 1024
#define DSTATE 64
#define DINNER 2048
#define MROWS 8192            // BATCH*SEQ
#define NCAT 1152             // Bcat rows: 1024 (dt) + 64 (xp) + 64 pad
#define NCHUNK 64             // scan chunks
#define LCHUNK 64             // steps per chunk

typedef __attribute__((ext_vector_type(8))) __bf16 bf16x8;
typedef __attribute__((ext_vector_type(8))) short short8;
typedef __attribute__((ext_vector_type(4))) float floatx4;

__device__ inline float bf2f(short s) {
  union { unsigned u; float f; } c;
  c.u = ((unsigned)(unsigned short)s) << 16;
  return c.f;
}
__device__ inline short f2bf(float f) {
  union { float f; unsigned u; } c; c.f = f;
  unsigned r = 0x7fffu + ((c.u >> 16) & 1u);
  return (short)((c.u + r) >> 16);
}
__device__ inline float silu_f(float v) {
  return v * __builtin_amdgcn_rcpf(1.f + __expf(-v));
}
__device__ inline float softplus_f(float v) {
  return fmaxf(v, 0.f) + log1pf(__expf(-fabsf(v)));
}
// async global->LDS, 16B per lane. LDS dest = wave-uniform base + lane*16.
__device__ inline void gld_lds16(const void* g, void* l) {
  __builtin_amdgcn_global_load_lds(
      (__attribute__((address_space(1))) void*)g,
      (__attribute__((address_space(3))) void*)l, 16, 0, 0);
}

// panel-staged bf16 layout: panel = 16 rows, stored contiguously (K*32 bytes),
// inside: [k-chunk of 8][row-in-panel 16][8 elems].  element (r,k):
__device__ inline size_t permOff(int r, int k, int K) {
  return (((size_t)(r >> 4) * (K >> 3) + (k >> 3)) << 7) + ((r & 15) << 3) + (k & 7);
}

// in_proj column pairing: xi col c -> newrow ((c>>4)<<5)|(c&15);
// g col c (orig 2048+c) -> newrow ((c>>4)<<5)|16|(c&15). Each 32-row block of
// Wt_in = 16 xi cols + their 16 matching g cols -> GEMM1 fragment pair
// (ct even, ct odd) holds xi and g for the SAME phi in the SAME lane.
__device__ inline int inproj_remap(int oc) {
  const int c = (oc < DINNER) ? oc : oc - DINNER;
  return ((c >> 4) << 5) | ((oc < DINNER) ? 0 : 16) | (c & 15);
}

// ---------------- fused pre-pass ---------------------------------------------
#define PP0 4096
#define PP1 (PP0 + 4096)
#define PP2 (PP1 + 2048)
#define PP3 (PP2 + 128)
#define PP4 (PP3 + 2048)

__device__ void tile_transpose_perm(const float* __restrict__ in, short* __restrict__ out,
                                    int R, int C, int bx, int by, float (*tile)[33],
                                    int remap) {
  const int tx = threadIdx.x & 31, ty = threadIdx.x >> 5;   // 32 x 8
  const int cb = bx * 32, rb = by * 32;
#pragma unroll
  for (int i = 0; i < 32; i += 8) {
    int r = rb + ty + i, c = cb + tx;
    tile[ty + i][tx] = (r < R && c < C) ? in[(size_t)r * C + c] : 0.f;
  }
  __syncthreads();
#pragma unroll
  for (int i = 0; i < 32; i += 8) {
    int orow = cb + ty + i, oc = rb + tx;   // out(row=orow, k=oc) = in[oc][orow]
    if (orow < C && oc < R) {
      int nr = remap ? inproj_remap(orow) : orow;
      out[permOff(nr, oc, R)] = f2bf(tile[tx][ty + i]);
    }
  }
}

__global__ void prepass_kernel(const float* __restrict__ x, short* __restrict__ x_bf,
                               const float* __restrict__ W_in, short* __restrict__ Wt_in,
                               const float* __restrict__ W_dt, const float* __restrict__ W_xp,
                               short* __restrict__ Bcat,
                               const float* __restrict__ W_out, short* __restrict__ Wt_out) {
  __shared__ float tile[32][33];
  const int blk = blockIdx.x;
  if (blk < PP0) {
    int o = blk * 256 + threadIdx.x;            // [0, 1M) 16B groups
    int m = o & 15, rest = o >> 4;
    int c = rest & 127, p = rest >> 7;          // K/8 = 128 chunks
    const float* src = x + ((size_t)(p * 16 + m)) * 1024 + c * 8;
    float4 v0 = ((const float4*)src)[0];
    float4 v1 = ((const float4*)src)[1];
    short8 ov;
    ov[0] = f2bf(v0.x); ov[1] = f2bf(v0.y); ov[2] = f2bf(v0.z); ov[3] = f2bf(v0.w);
    ov[4] = f2bf(v1.x); ov[5] = f2bf(v1.y); ov[6] = f2bf(v1.z); ov[7] = f2bf(v1.w);
    ((short8*)x_bf)[o] = ov;
  } else if (blk < PP1) {
    int t = blk - PP0;
    tile_transpose_perm(W_in, Wt_in, 1024, 4096, t & 127, t >> 7, tile, 1);
  } else if (blk < PP2) {
    int t = blk - PP1;
    tile_transpose_perm(W_dt, Bcat, 2048, 1024, t & 31, t >> 5, tile, 0);
  } else if (blk < PP3) {
    int t = blk - PP2;
    tile_transpose_perm(W_xp, Bcat + (size_t)1024 * DINNER, 2048, 64, t & 1, t >> 1, tile, 0);
  } else {
    int t = blk - PP3;
    tile_transpose_perm(W_out, Wt_out, 2048, 1024, t & 31, t >> 5, tile, 0);
  }
}

// ---------------- 256x256 read-ahead bf16 GEMM (counted-lgkm pipeline) -------
// R5-verified schedule (80.4us/36% on GEMM1). 512 thr = 8 waves (2M x 4N);
// wave owns 128x64 = 8x4 frags. BK=64, 2 LDS buffers x 64KB = 128KB.
// Read group for MFMA cluster k+1 issued BEFORE cluster k's MFMAs -> compiler
// emits counted lgkmcnt; LDS port overlaps matrix pipe. Two barriers/tile,
// counted vmcnt(4) twice/tile; never drains mid-loop. (Ledger in R5 notes.)
// NOTE (R8 lesson): this schedule is verified ONLY at 8 waves (2 waves/SIMD).
// The 4-wave (1/SIMD) full-K morph ran 20x slower (exposed stalls + suspected
// compiler DMA-vs-LDS ordering) -- do not re-derive without disasm evidence.
// MODE 0: paired in_proj epilogue (remapped Wt_in): even ct frag = xi col phi,
//   odd ct frag = g col phi (same lane). Writes xi=silu(.) to out0 and
//   prod=silu(xi)*silu(g) to out1 (panel-staged). s_sum applied downstream.
// MODE 1: raw bf16 split-K partials, row-major stride N.
template <int MODE, int KTOT, int KSL, int NT, int ZS>
__global__ __launch_bounds__(512, 2) void gemm256(
    const short* __restrict__ A, const short* __restrict__ Bt,
    const float* __restrict__ bias,
    void* __restrict__ out0, void* __restrict__ out1)
{
  __shared__ __attribute__((aligned(16))) short sLds[65536];   // 128 KiB

  const int tid = threadIdx.x;
  const int lane = tid & 63;
  const int w = tid >> 6;              // 0..7
  const int wr = w >> 2, wc = w & 3;   // 2 x 4 wave grid
  const int m = lane & 15, quad = lane >> 4;

  const int xcd = blockIdx.x & 7;
  const int q = blockIdx.x >> 3;
  const int mt = xcd * 4 + (q & 3);
  const int rest = q >> 2;
  const int ntile = rest % NT;
  const int z = rest / NT;
  const int bM = mt * 256, bN = ntile * 256;
  const int kbeg = z * KSL;

  floatx4 acc[8][4] = {};

  const size_t PS = (size_t)KTOT * 16;   // panel stride in shorts
  const short* AgA = A  + ((size_t)(bM >> 4) + w) * PS + (size_t)kbeg * 16 + lane * 8;
  const short* AgB = AgA + 8 * PS;
  const short* BgA = Bt + ((size_t)(bN >> 4) + w) * PS + (size_t)kbeg * 16 + lane * 8;
  const short* BgB = BgA + 8 * PS;

  constexpr int KT = KSL / 64;           // K-tiles of 64 (>= 2)

  auto STAGE_Q = [&](int t, int qq) {    // quarter qq: 0:A-kh0 1:B-kh0 2:A-kh1 3:B-kh1
    const size_t go = (size_t)t * 1024 + (size_t)(qq >> 1) * 512;
    short* d = sLds + ((t & 1) << 15) + ((qq & 1) << 14) + ((qq >> 1) << 13) + w * 512;
    const short* g0 = (qq & 1) ? BgA : AgA;   // panel w
    const short* g1 = (qq & 1) ? BgB : AgB;   // panel w+8
    gld_lds16(g0 + go, d);
    gld_lds16(g1 + go, d + 4096);
  };

  const int aoff = wr * 4096 + quad * 128 + m * 8;           // + rt*512 + kh*8192
  const int boff = 16384 + wc * 2048 + quad * 128 + m * 8;   // + ct*512 + kh*8192

  bf16x8 aA[4], aB[4], bA[4], bB[4];

  STAGE_Q(0, 0); STAGE_Q(0, 1); STAGE_Q(0, 2); STAGE_Q(0, 3);
  asm volatile("s_waitcnt vmcnt(4)" ::: "memory");
  asm volatile("s_barrier" ::: "memory");
  {
    const short* bs = sLds;
#pragma unroll
    for (int rt = 0; rt < 4; ++rt) aA[rt] = *(const bf16x8*)(bs + aoff + rt * 512);
#pragma unroll
    for (int ct = 0; ct < 4; ++ct) bA[ct] = *(const bf16x8*)(bs + boff + ct * 512);
    if (KT > 1) STAGE_Q(1, 0);
    __builtin_amdgcn_sched_barrier(0);
  }

#pragma unroll 1
  for (int t = 0; t < KT; ++t) {
    const short* bs = sLds + ((t & 1) << 15);
    const bool pf = (t + 1 < KT);

#pragma unroll
    for (int rt = 0; rt < 4; ++rt) aB[rt] = *(const bf16x8*)(bs + aoff + (4 + rt) * 512);
    if (pf) {
      STAGE_Q(t + 1, 1);
      asm volatile("s_waitcnt vmcnt(4)" ::: "memory");
    } else {
      asm volatile("s_waitcnt vmcnt(0)" ::: "memory");
    }
    __builtin_amdgcn_sched_barrier(0);
    __builtin_amdgcn_s_setprio(1);
#pragma unroll
    for (int rt = 0; rt < 4; ++rt)
#pragma unroll
      for (int ct = 0; ct < 4; ++ct)
        acc[rt][ct] = __builtin_amdgcn_mfma_f32_16x16x32_bf16(aA[rt], bA[ct], acc[rt][ct], 0, 0, 0);
    __builtin_amdgcn_s_setprio(0);
    __builtin_amdgcn_sched_barrier(0);

    asm volatile("s_waitcnt lgkmcnt(0)" ::: "memory");
    asm volatile("s_barrier" ::: "memory");
#pragma unroll
    for (int rt = 0; rt < 4; ++rt) aA[rt] = *(const bf16x8*)(bs + 8192 + aoff + rt * 512);
#pragma unroll
    for (int ct = 0; ct < 4; ++ct) bB[ct] = *(const bf16x8*)(bs + 8192 + boff + ct * 512);
    if (pf) STAGE_Q(t + 1, 2);
    __builtin_amdgcn_sched_barrier(0);
    __builtin_amdgcn_s_setprio(1);
#pragma unroll
    for (int rt = 0; rt < 4; ++rt)
#pragma unroll
      for (int ct = 0; ct < 4; ++ct)
        acc[4 + rt][ct] = __builtin_amdgcn_mfma_f32_16x16x32_bf16(aB[rt], bA[ct], acc[4 + rt][ct], 0, 0, 0);
    __builtin_amdgcn_s_setprio(0);
    __builtin_amdgcn_sched_barrier(0);

#pragma unroll
    for (int rt = 0; rt < 4; ++rt) aB[rt] = *(const bf16x8*)(bs + 8192 + aoff + (4 + rt) * 512);
    if (pf) {
      STAGE_Q(t + 1, 3);
      asm volatile("s_waitcnt vmcnt(4)" ::: "memory");
    }
    __builtin_amdgcn_sched_barrier(0);
    __builtin_amdgcn_s_setprio(1);
#pragma unroll
    for (int rt = 0; rt < 4; ++rt)
#pragma unroll
      for (int ct = 0; ct < 4; ++ct)
        acc[rt][ct] = __builtin_amdgcn_mfma_f32_16x16x32_bf16(aA[rt], bB[ct], acc[rt][ct], 0, 0, 0);
    __builtin_amdgcn_s_setprio(0);
    __builtin_amdgcn_sched_barrier(0);

    if (pf) {
      asm volatile("s_waitcnt lgkmcnt(0)" ::: "memory");
      asm volatile("s_barrier" ::: "memory");
      const short* bs2 = sLds + (((t + 1) & 1) << 15);
#pragma unroll
      for (int rt = 0; rt < 4; ++rt) aA[rt] = *(const bf16x8*)(bs2 + aoff + rt * 512);
#pragma unroll
      for (int ct = 0; ct < 4; ++ct) bA[ct] = *(const bf16x8*)(bs2 + boff + ct * 512);
      if (t + 2 < KT) STAGE_Q(t + 2, 0);
      __builtin_amdgcn_sched_barrier(0);
    }
    __builtin_amdgcn_s_setprio(1);
#pragma unroll
    for (int rt = 0; rt < 4; ++rt)
#pragma unroll
      for (int ct = 0; ct < 4; ++ct)
        acc[4 + rt][ct] = __builtin_amdgcn_mfma_f32_16x16x32_bf16(aB[rt], bB[ct], acc[4 + rt][ct], 0, 0, 0);
    __builtin_amdgcn_s_setprio(0);
    __builtin_amdgcn_sched_barrier(0);
  }

  const int rowbase = bM + wr * 128;
  const int colbase = bN + wc * 64;

  if constexpr (MODE == 0) {
    // paired in_proj epilogue: even/odd ct frags = xi/g at the same phi.
    short* xid = (short*)out0;
    short* prd = (short*)out1;
#pragma unroll
    for (int cp = 0; cp < 2; ++cp) {
      const int newcolE = colbase + cp * 32 + m;
      const int phi = ((newcolE >> 5) << 4) | (newcolE & 15);   // 0..2047
      const float bxi = bias[phi];
      const float bg  = bias[DINNER + phi];
#pragma unroll
      for (int rt = 0; rt < 8; ++rt) {
        const size_t rowPan = ((size_t)(rowbase >> 4) + rt) << 8;
        const size_t base = ((rowPan + (phi >> 3)) << 7) + (phi & 7) + ((size_t)quad * 32);
#pragma unroll
        for (int reg = 0; reg < 4; ++reg) {
          const float xv = silu_f(acc[rt][2 * cp][reg] + bxi);
          const float gv = silu_f(acc[rt][2 * cp + 1][reg] + bg);
          xid[base + reg * 8] = f2bf(xv);
          prd[base + reg * 8] = f2bf(xv * gv);
        }
      }
    }
  } else {
    constexpr int N = NT * 256;
    short* dst = (short*)out0 + (size_t)z * MROWS * N;
#pragma unroll
    for (int rt = 0; rt < 8; ++rt)
#pragma unroll
      for (int ct = 0; ct < 4; ++ct) {
        const int col = colbase + ct * 16 + m;
#pragma unroll
        for (int reg = 0; reg < 4; ++reg) {
          const int r = rowbase + rt * 16 + quad * 4 + reg;
          dst[(size_t)r * N + col] = f2bf(acc[rt][ct][reg]);
        }
      }
  }
}

// ---------------- skinny xp GEMM: bx partials = xi @ W_xp (fp32) -------------
// 32KB LDS -> 4 blocks/CU = 4 waves/SIMD (why this 4-wave kernel is fine
// while R8's 96KB 1-wave/SIMD gemm128 was not).
__global__ __launch_bounds__(256) void xp_gemm(const short* __restrict__ xi,
                                               const short* __restrict__ Bxp,
                                               float* __restrict__ bxp) {
  __shared__ __attribute__((aligned(16))) short sA[2][4096];
  __shared__ __attribute__((aligned(16))) short sB[2][4096];
  const int tid = threadIdx.x, lane = tid & 63, w = tid >> 6;
  const int m = lane & 15, quad = lane >> 4;
  const int z = blockIdx.x >> 7;            // K-slice
  const int rb = (blockIdx.x & 127) * 64;   // row base
  const size_t PS = (size_t)2048 * 16;      // panel stride (shorts)
  const short* Ag = xi  + ((size_t)(rb >> 4) + w) * PS + (size_t)z * 1024 * 16 + lane * 8;
  const short* Bg = Bxp + (size_t)w * PS + (size_t)z * 1024 * 16 + lane * 8;
  floatx4 acc[4] = {};
  auto STAGE = [&](int t) {                 // 4 gld_lds per wave
    const size_t go = (size_t)t * 1024;
    short* da = sA[t & 1] + w * 1024;
    short* db = sB[t & 1] + w * 1024;
    gld_lds16(Ag + go, da); gld_lds16(Ag + go + 512, da + 512);
    gld_lds16(Bg + go, db); gld_lds16(Bg + go + 512, db + 512);
  };
  STAGE(0);
#pragma unroll 1
  for (int t = 0; t < 16; ++t) {
    __builtin_amdgcn_s_barrier();
    if (t + 1 < 16) {
      STAGE(t + 1);
      asm volatile("s_waitcnt vmcnt(4)" ::: "memory");
    } else {
      asm volatile("s_waitcnt vmcnt(0)" ::: "memory");
    }
    __builtin_amdgcn_s_barrier();
    const short* a0 = sA[t & 1] + w * 1024 + quad * 128 + m * 8;
    const short* b0 = sB[t & 1] + quad * 128 + m * 8;
#pragma unroll
    for (int kh = 0; kh < 2; ++kh) {
      bf16x8 a = *(const bf16x8*)(a0 + kh * 512);
#pragma unroll
      for (int ct = 0; ct < 4; ++ct) {
        bf16x8 b = *(const bf16x8*)(b0 + ct * 1024 + kh * 512);
        acc[ct] = __builtin_amdgcn_mfma_f32_16x16x32_bf16(a, b, acc[ct], 0, 0, 0);
      }
    }
  }
  float* dst = bxp + (size_t)z * MROWS * DSTATE;
#pragma unroll
  for (int ct = 0; ct < 4; ++ct)
#pragma unroll
    for (int reg = 0; reg < 4; ++reg)
      dst[(size_t)(rb + w * 16 + quad * 4 + reg) * DSTATE + ct * 16 + m] = acc[ct][reg];
}

// ---------------- split-K combine epilogues ----------------------------------
// G2: one wave per row; p[2][8192][1024] bf16 dt-partials -> md_sum
__global__ void g2_epilogue(const short* __restrict__ p, const float* __restrict__ b_dt,
                            float* __restrict__ md_sum) {
  const int row = blockIdx.x * 4 + (threadIdx.x >> 6);
  const int lane = threadIdx.x & 63;
  const size_t base0 = (size_t)row * 1024;
  const size_t base1 = base0 + (size_t)MROWS * 1024;
  short8 a0 = *(const short8*)(p + base0 + lane * 16);
  short8 a1 = *(const short8*)(p + base0 + lane * 16 + 8);
  short8 c0 = *(const short8*)(p + base1 + lane * 16);
  short8 c1 = *(const short8*)(p + base1 + lane * 16 + 8);
  float s = 0.f;
#pragma unroll
  for (int j = 0; j < 8; ++j) {
    s += softplus_f(bf2f(a0[j]) + bf2f(c0[j]) + b_dt[lane * 16 + j]);
    s += softplus_f(bf2f(a1[j]) + bf2f(c1[j]) + b_dt[lane * 16 + 8 + j]);
  }
  s += __shfl_xor(s, 1);  s += __shfl_xor(s, 2);  s += __shfl_xor(s, 4);
  s += __shfl_xor(s, 8);  s += __shfl_xor(s, 16); s += __shfl_xor(s, 32);
  if (lane == 0) md_sum[row] = s;
}

// G4: out = s_sum*(p0 + p1) + b_out + x*D   (fp32 row-major [8192,1024])
// s_sum applied here (linearity of matmul in A-rows). Batched 8 rows/block:
// hoists b_out/Dv loads 8x and cuts launch width 8192 -> 1024 blocks.
__global__ void g4_epilogue(const short* __restrict__ p, const float* __restrict__ b_out,
                            const float* __restrict__ x, const float* __restrict__ Dv,
                            const float* __restrict__ s_sum, float* __restrict__ out) {
  const int c = threadIdx.x * 4;
  const float bo0 = b_out[c + 0], bo1 = b_out[c + 1];
  const float bo2 = b_out[c + 2], bo3 = b_out[c + 3];
  const float d0 = Dv[c + 0], d1 = Dv[c + 1], d2 = Dv[c + 2], d3 = Dv[c + 3];
#pragma unroll
  for (int i = 0; i < 8; ++i) {
    const int r = blockIdx.x * 8 + i;
    const float s = s_sum[r];
    const size_t o = (size_t)r * DMODEL + c;
    short4 a0 = *(const short4*)(p + o);
    short4 a1 = *(const short4*)(p + (size_t)MROWS * DMODEL + o);
    float4 xv = *(const float4*)(x + o);
    float4 ov;
    ov.x = s * (bf2f(a0.x) + bf2f(a1.x)) + bo0 + xv.x * d0;
    ov.y = s * (bf2f(a0.y) + bf2f(a1.y)) + bo1 + xv.y * d1;
    ov.z = s * (bf2f(a0.z) + bf2f(a1.z)) + bo2 + xv.z * d2;
    ov.w = s * (bf2f(a0.w) + bf2f(a1.w)) + bo3 + xv.w * d3;
    *(float4*)(out + o) = ov;
  }
}

// ---------------- chunked selective scan (2 phases) --------------------------
// bx value = bxp[0][row][n] + bxp[1][row][n] + b_xp[n] (fp32 split-K partials)
__global__ void scan_phase1(const float* __restrict__ md_sum, const float* __restrict__ A_log,
                            const float* __restrict__ bxp, const float* __restrict__ b_xp,
                            float* __restrict__ chunk_prod, float* __restrict__ chunk_end) {
  const int n = threadIdx.x;                // 0..63 (state dim)
  const int c = blockIdx.x & (NCHUNK - 1);  // chunk
  const int b = blockIdx.x >> 6;            // batch
  const float An = -__expf(A_log[n]);
  const float bxn = b_xp[n];
  const float* bx0 = bxp;
  const float* bx1 = bxp + (size_t)MROWS * DSTATE;
  float prod = 1.f, st = 0.f;
  const int t0 = c * LCHUNK;
#pragma unroll 4
  for (int i = 0; i < LCHUNK; ++i) {
    const int t = t0 + i;
    const float md = md_sum[b * SEQ + t] * (1.f / DMODEL);
    const float a = __expf(An * md);
    const size_t idx = ((size_t)(b * SEQ + t)) * DSTATE + n;
    st = a * st + (bx0[idx] + bx1[idx] + bxn);
    prod *= a;
  }
  chunk_prod[(b * NCHUNK + c) * DSTATE + n] = prod;
  chunk_end [(b * NCHUNK + c) * DSTATE + n] = st;
}

// phase3: redo own chunk-prefix, recompute a=exp(An*md), emit s_sum
__global__ void scan_phase3(const float* __restrict__ md_sum, const float* __restrict__ A_log,
                            const float* __restrict__ bxp, const float* __restrict__ b_xp,
                            const float* __restrict__ chunk_prod,
                            const float* __restrict__ chunk_end,
                            float* __restrict__ s_sum) {
  const int n = threadIdx.x;
  const int c = blockIdx.x & (NCHUNK - 1);
  const int b = blockIdx.x >> 6;
  const float An = -__expf(A_log[n]);
  const float bxn = b_xp[n];
  const float* bx0 = bxp;
  const float* bx1 = bxp + (size_t)MROWS * DSTATE;
  float st = 0.f;
#pragma unroll 4
  for (int cc = 0; cc < c; ++cc) {
    const size_t idx = ((size_t)(b * NCHUNK + cc)) * DSTATE + n;
    st = chunk_prod[idx] * st + chunk_end[idx];
  }
  const int t0 = c * LCHUNK;
#pragma unroll 4
  for (int i = 0; i < LCHUNK; ++i) {
    const int t = t0 + i;
    const float md = md_sum[b * SEQ + t] * (1.f / DMODEL);
    const float a = __expf(An * md);
    const size_t idx = ((size_t)(b * SEQ + t)) * DSTATE + n;
    st = a * st + (bx0[idx] + bx1[idx] + bxn);
    float v = st;
    v += __shfl_xor(v, 32); v += __shfl_xor(v, 16); v += __shfl_xor(v, 8);
    v += __shfl_xor(v, 4);  v += __shfl_xor(v, 2);  v += __shfl_xor(v, 1);
    if (n == 0) s_sum[b * SEQ + t] = v;
  }
}

// ---------------- launch ------------------------------------------------------
extern "C" void kernel_launch(void* const* d_in, const int* in_sizes, int n_in,
                              void* d_out, int out_size, void* d_ws, size_t ws_size,
                              hipStream_t stream) {
  const float* x     = (const float*)d_in[0];
  const float* W_in  = (const float*)d_in[1];
  const float* b_in  = (const float*)d_in[2];
  const float* W_xp  = (const float*)d_in[3];
  const float* b_xp  = (const float*)d_in[4];
  const float* W_dt  = (const float*)d_in[5];
  const float* b_dt  = (const float*)d_in[6];
  const float* W_out = (const float*)d_in[7];
  const float* b_out = (const float*)d_in[8];
  const float* A_log = (const float*)d_in[9];
  const float* Dv    = (const float*)d_in[10];

  char* ws = (char*)d_ws;
  size_t off = 0;
  auto alloc = [&](size_t bytes) -> void* {
    void* p = (void*)(ws + off);
    off += (bytes + 255) & ~(size_t)255;
    return p;
  };
  short* x_bf    = (short*)alloc((size_t)MROWS * DMODEL * 2);
  short* Wt_in   = (short*)alloc((size_t)4096 * 1024 * 2);
  short* Bcat    = (short*)alloc((size_t)NCAT * DINNER * 2);
  short* Wt_out  = (short*)alloc((size_t)1024 * 2048 * 2);
  short* xi      = (short*)alloc((size_t)MROWS * DINNER * 2);   // also G4 partials
  short* prod    = (short*)alloc((size_t)MROWS * DINNER * 2);   // silu(xi)*silu(g)
  short* p2      = (short*)alloc((size_t)2 * MROWS * 1024 * 2); // G2 dt partials
  float* md_sum  = (float*)alloc((size_t)MROWS * 4);
  float* bxp     = (float*)alloc((size_t)2 * MROWS * DSTATE * 4); // xp partials
  float* cprod   = (float*)alloc((size_t)2 * NCHUNK * DSTATE * 4);
  float* cend    = (float*)alloc((size_t)2 * NCHUNK * DSTATE * 4);
  float* s_sum   = (float*)alloc((size_t)MROWS * 4);

  // fused pre-pass: x->bf16 (panel-staged) + all 4 weight transposes
  // (W_in transposed with the xi/g column-pairing remap)
  prepass_kernel<<<PP4, 256, 0, stream>>>(x, x_bf, W_in, Wt_in, W_dt, W_xp, Bcat, W_out, Wt_out);

  // GEMM1: in_proj, paired epilogue -> xi + prod (ymul folded in)
  gemm256<0, 1024, 1024, 16, 1><<<512, 512, 0, stream>>>(x_bf, Wt_in, b_in, xi, prod);
  // GEMM2-dt: 256^2 pipeline, split-K=2, N=1024 -> one clean round (256 blocks)
  gemm256<1, 2048, 1024, 4, 2><<<256, 512, 0, stream>>>(xi, Bcat, nullptr, p2, nullptr);
  // GEMM2-xp: skinny N=64, fp32 partials straight into bxp
  xp_gemm<<<256, 256, 0, stream>>>(xi, Bcat + (size_t)1024 * DINNER, bxp);
  // combine dt partials -> softplus rowsum
  g2_epilogue<<<MROWS / 4, 256, 0, stream>>>(p2, b_dt, md_sum);
  // selective scan (phase3 self-computes its chunk prefix)
  scan_phase1<<<2 * NCHUNK, DSTATE, 0, stream>>>(md_sum, A_log, bxp, b_xp, cprod, cend);
  scan_phase3<<<2 * NCHUNK, DSTATE, 0, stream>>>(md_sum, A_log, bxp, b_xp, cprod, cend, s_sum);
  // GEMM4: P = prod @ W_out, split-K=2 partials into xi's slot
  gemm256<1, 2048, 1024, 4, 2><<<256, 512, 0, stream>>>(prod, Wt_out, nullptr, xi, nullptr);
  // epilogue applies s_sum scale + b_out + x*D (8 rows/block)
  g4_epilogue<<<MROWS / 8, 256, 0, stream>>>(xi, b_out, x, Dv, s_sum, (float*)d_out);
}

// Round 10
// 356.281 us; speedup vs baseline: 1.5175x; 1.0151x over previous
//
#include <hip/hip_runtime.h>

#define SEQ 4096
#define DMODEL 1024
#define DSTATE 64
#define DINNER 2048
#define MROWS 8192            // BATCH*SEQ
#define NCAT 1152             // Bcat rows: 1024 (dt) + 64 (xp) + 64 pad
#define NCHUNK 64             // scan chunks
#define LCHUNK 64             // steps per chunk

typedef __attribute__((ext_vector_type(8))) __bf16 bf16x8;
typedef __attribute__((ext_vector_type(8))) short short8;
typedef __attribute__((ext_vector_type(4))) float floatx4;

__device__ inline float bf2f(short s) {
  union { unsigned u; float f; } c;
  c.u = ((unsigned)(unsigned short)s) << 16;
  return c.f;
}
__device__ inline short f2bf(float f) {
  union { float f; unsigned u; } c; c.f = f;
  unsigned r = 0x7fffu + ((c.u >> 16) & 1u);
  return (short)((c.u + r) >> 16);
}
__device__ inline float silu_f(float v) {
  return v * __builtin_amdgcn_rcpf(1.f + __expf(-v));
}
__device__ inline float softplus_f(float v) {
  return fmaxf(v, 0.f) + log1pf(__expf(-fabsf(v)));
}
// async global->LDS, 16B per lane. LDS dest = wave-uniform base + lane*16.
__device__ inline void gld_lds16(const void* g, void* l) {
  __builtin_amdgcn_global_load_lds(
      (__attribute__((address_space(1))) void*)g,
      (__attribute__((address_space(3))) void*)l, 16, 0, 0);
}

// panel-staged bf16 layout: panel = 16 rows, stored contiguously (K*32 bytes),
// inside: [k-chunk of 8][row-in-panel 16][8 elems].  element (r,k):
__device__ inline size_t permOff(int r, int k, int K) {
  return (((size_t)(r >> 4) * (K >> 3) + (k >> 3)) << 7) + ((r & 15) << 3) + (k & 7);
}

// in_proj column pairing: xi col c -> newrow ((c>>4)<<5)|(c&15);
// g col c (orig 2048+c) -> newrow ((c>>4)<<5)|16|(c&15). Each 32-row block of
// Wt_in = 16 xi cols + their 16 matching g cols -> GEMM1 fragment pair
// (ct even, ct odd) holds xi and g for the SAME phi in the SAME lane.
__device__ inline int inproj_remap(int oc) {
  const int c = (oc < DINNER) ? oc : oc - DINNER;
  return ((c >> 4) << 5) | ((oc < DINNER) ? 0 : 16) | (c & 15);
}

// ---------------- fused pre-pass ---------------------------------------------
#define PP0 4096
#define PP1 (PP0 + 4096)
#define PP2 (PP1 + 2048)
#define PP3 (PP2 + 128)
#define PP4 (PP3 + 2048)

// R10: write phase vectorized to short8. permOff(r, k..k+7) for k aligned-8
// is 8 contiguous shorts; per 16-lane group stores land as one contiguous
// 256B burst. Previous version emitted 1024 scattered 2B stores per tile.
// All matrix dims here are multiples of 32 -> no partial tiles; guards kept
// for safety. LDS reads in the write phase are stride-1 per j (2-way max,
// free per bank rules).
__device__ void tile_transpose_perm(const float* __restrict__ in, short* __restrict__ out,
                                    int R, int C, int bx, int by, float (*tile)[33],
                                    int remap) {
  const int tx = threadIdx.x & 31, ty = threadIdx.x >> 5;   // 32 x 8
  const int cb = bx * 32, rb = by * 32;
#pragma unroll
  for (int i = 0; i < 32; i += 8) {
    int r = rb + ty + i, c = cb + tx;
    tile[ty + i][tx] = (r < R && c < C) ? in[(size_t)r * C + c] : 0.f;
  }
  __syncthreads();
  const int t = threadIdx.x;
  if (t < 128) {
    const int ocol = t & 31;          // output row within tile (= input col)
    const int ko = t >> 5;            // k-octet 0..3 (= input row block /8)
    const int orow = cb + ocol;
    const int k0 = rb + ko * 8;
    if (orow < C && k0 < R) {
      const int nr = remap ? inproj_remap(orow) : orow;
      short8 v;
#pragma unroll
      for (int j = 0; j < 8; ++j) v[j] = f2bf(tile[ko * 8 + j][ocol]);
      *(short8*)(out + permOff(nr, k0, R)) = v;
    }
  }
}

__global__ void prepass_kernel(const float* __restrict__ x, short* __restrict__ x_bf,
                               const float* __restrict__ W_in, short* __restrict__ Wt_in,
                               const float* __restrict__ W_dt, const float* __restrict__ W_xp,
                               short* __restrict__ Bcat,
                               const float* __restrict__ W_out, short* __restrict__ Wt_out) {
  __shared__ float tile[32][33];
  const int blk = blockIdx.x;
  if (blk < PP0) {
    int o = blk * 256 + threadIdx.x;            // [0, 1M) 16B groups
    int m = o & 15, rest = o >> 4;
    int c = rest & 127, p = rest >> 7;          // K/8 = 128 chunks
    const float* src = x + ((size_t)(p * 16 + m)) * 1024 + c * 8;
    float4 v0 = ((const float4*)src)[0];
    float4 v1 = ((const float4*)src)[1];
    short8 ov;
    ov[0] = f2bf(v0.x); ov[1] = f2bf(v0.y); ov[2] = f2bf(v0.z); ov[3] = f2bf(v0.w);
    ov[4] = f2bf(v1.x); ov[5] = f2bf(v1.y); ov[6] = f2bf(v1.z); ov[7] = f2bf(v1.w);
    ((short8*)x_bf)[o] = ov;
  } else if (blk < PP1) {
    int t = blk - PP0;
    tile_transpose_perm(W_in, Wt_in, 1024, 4096, t & 127, t >> 7, tile, 1);
  } else if (blk < PP2) {
    int t = blk - PP1;
    tile_transpose_perm(W_dt, Bcat, 2048, 1024, t & 31, t >> 5, tile, 0);
  } else if (blk < PP3) {
    int t = blk - PP2;
    tile_transpose_perm(W_xp, Bcat + (size_t)1024 * DINNER, 2048, 64, t & 1, t >> 1, tile, 0);
  } else {
    int t = blk - PP3;
    tile_transpose_perm(W_out, Wt_out, 2048, 1024, t & 31, t >> 5, tile, 0);
  }
}

// ---------------- 256x256 read-ahead bf16 GEMM (counted-lgkm pipeline) -------
// R5-verified schedule (80.4us/36% on GEMM1). 512 thr = 8 waves (2M x 4N);
// wave owns 128x64 = 8x4 frags. BK=64, 2 LDS buffers x 64KB = 128KB.
// Read group for MFMA cluster k+1 issued BEFORE cluster k's MFMAs -> compiler
// emits counted lgkmcnt; LDS port overlaps matrix pipe. Two barriers/tile,
// counted vmcnt(4) twice/tile; never drains mid-loop. (Ledger in R5 notes.)
// NOTE (R8 lesson): this schedule is verified ONLY at 8 waves (2 waves/SIMD).
// The 4-wave (1/SIMD) full-K morph ran 20x slower (exposed stalls + suspected
// compiler DMA-vs-LDS ordering) -- do not re-derive without disasm evidence.
// MODE 0: paired in_proj epilogue (remapped Wt_in): even ct frag = xi col phi,
//   odd ct frag = g col phi (same lane). Writes xi=silu(.) to out0 and
//   prod=silu(xi)*silu(g) to out1 (panel-staged). s_sum applied downstream.
// MODE 1: raw bf16 split-K partials, row-major stride N.
template <int MODE, int KTOT, int KSL, int NT, int ZS>
__global__ __launch_bounds__(512, 2) void gemm256(
    const short* __restrict__ A, const short* __restrict__ Bt,
    const float* __restrict__ bias,
    void* __restrict__ out0, void* __restrict__ out1)
{
  __shared__ __attribute__((aligned(16))) short sLds[65536];   // 128 KiB

  const int tid = threadIdx.x;
  const int lane = tid & 63;
  const int w = tid >> 6;              // 0..7
  const int wr = w >> 2, wc = w & 3;   // 2 x 4 wave grid
  const int m = lane & 15, quad = lane >> 4;

  const int xcd = blockIdx.x & 7;
  const int q = blockIdx.x >> 3;
  const int mt = xcd * 4 + (q & 3);
  const int rest = q >> 2;
  const int ntile = rest % NT;
  const int z = rest / NT;
  const int bM = mt * 256, bN = ntile * 256;
  const int kbeg = z * KSL;

  floatx4 acc[8][4] = {};

  const size_t PS = (size_t)KTOT * 16;   // panel stride in shorts
  const short* AgA = A  + ((size_t)(bM >> 4) + w) * PS + (size_t)kbeg * 16 + lane * 8;
  const short* AgB = AgA + 8 * PS;
  const short* BgA = Bt + ((size_t)(bN >> 4) + w) * PS + (size_t)kbeg * 16 + lane * 8;
  const short* BgB = BgA + 8 * PS;

  constexpr int KT = KSL / 64;           // K-tiles of 64 (>= 2)

  auto STAGE_Q = [&](int t, int qq) {    // quarter qq: 0:A-kh0 1:B-kh0 2:A-kh1 3:B-kh1
    const size_t go = (size_t)t * 1024 + (size_t)(qq >> 1) * 512;
    short* d = sLds + ((t & 1) << 15) + ((qq & 1) << 14) + ((qq >> 1) << 13) + w * 512;
    const short* g0 = (qq & 1) ? BgA : AgA;   // panel w
    const short* g1 = (qq & 1) ? BgB : AgB;   // panel w+8
    gld_lds16(g0 + go, d);
    gld_lds16(g1 + go, d + 4096);
  };

  const int aoff = wr * 4096 + quad * 128 + m * 8;           // + rt*512 + kh*8192
  const int boff = 16384 + wc * 2048 + quad * 128 + m * 8;   // + ct*512 + kh*8192

  bf16x8 aA[4], aB[4], bA[4], bB[4];

  STAGE_Q(0, 0); STAGE_Q(0, 1); STAGE_Q(0, 2); STAGE_Q(0, 3);
  asm volatile("s_waitcnt vmcnt(4)" ::: "memory");
  asm volatile("s_barrier" ::: "memory");
  {
    const short* bs = sLds;
#pragma unroll
    for (int rt = 0; rt < 4; ++rt) aA[rt] = *(const bf16x8*)(bs + aoff + rt * 512);
#pragma unroll
    for (int ct = 0; ct < 4; ++ct) bA[ct] = *(const bf16x8*)(bs + boff + ct * 512);
    if (KT > 1) STAGE_Q(1, 0);
    __builtin_amdgcn_sched_barrier(0);
  }

#pragma unroll 1
  for (int t = 0; t < KT; ++t) {
    const short* bs = sLds + ((t & 1) << 15);
    const bool pf = (t + 1 < KT);

#pragma unroll
    for (int rt = 0; rt < 4; ++rt) aB[rt] = *(const bf16x8*)(bs + aoff + (4 + rt) * 512);
    if (pf) {
      STAGE_Q(t + 1, 1);
      asm volatile("s_waitcnt vmcnt(4)" ::: "memory");
    } else {
      asm volatile("s_waitcnt vmcnt(0)" ::: "memory");
    }
    __builtin_amdgcn_sched_barrier(0);
    __builtin_amdgcn_s_setprio(1);
#pragma unroll
    for (int rt = 0; rt < 4; ++rt)
#pragma unroll
      for (int ct = 0; ct < 4; ++ct)
        acc[rt][ct] = __builtin_amdgcn_mfma_f32_16x16x32_bf16(aA[rt], bA[ct], acc[rt][ct], 0, 0, 0);
    __builtin_amdgcn_s_setprio(0);
    __builtin_amdgcn_sched_barrier(0);

    asm volatile("s_waitcnt lgkmcnt(0)" ::: "memory");
    asm volatile("s_barrier" ::: "memory");
#pragma unroll
    for (int rt = 0; rt < 4; ++rt) aA[rt] = *(const bf16x8*)(bs + 8192 + aoff + rt * 512);
#pragma unroll
    for (int ct = 0; ct < 4; ++ct) bB[ct] = *(const bf16x8*)(bs + 8192 + boff + ct * 512);
    if (pf) STAGE_Q(t + 1, 2);
    __builtin_amdgcn_sched_barrier(0);
    __builtin_amdgcn_s_setprio(1);
#pragma unroll
    for (int rt = 0; rt < 4; ++rt)
#pragma unroll
      for (int ct = 0; ct < 4; ++ct)
        acc[4 + rt][ct] = __builtin_amdgcn_mfma_f32_16x16x32_bf16(aB[rt], bA[ct], acc[4 + rt][ct], 0, 0, 0);
    __builtin_amdgcn_s_setprio(0);
    __builtin_amdgcn_sched_barrier(0);

#pragma unroll
    for (int rt = 0; rt < 4; ++rt) aB[rt] = *(const bf16x8*)(bs + 8192 + aoff + (4 + rt) * 512);
    if (pf) {
      STAGE_Q(t + 1, 3);
      asm volatile("s_waitcnt vmcnt(4)" ::: "memory");
    }
    __builtin_amdgcn_sched_barrier(0);
    __builtin_amdgcn_s_setprio(1);
#pragma unroll
    for (int rt = 0; rt < 4; ++rt)
#pragma unroll
      for (int ct = 0; ct < 4; ++ct)
        acc[rt][ct] = __builtin_amdgcn_mfma_f32_16x16x32_bf16(aA[rt], bB[ct], acc[rt][ct], 0, 0, 0);
    __builtin_amdgcn_s_setprio(0);
    __builtin_amdgcn_sched_barrier(0);

    if (pf) {
      asm volatile("s_waitcnt lgkmcnt(0)" ::: "memory");
      asm volatile("s_barrier" ::: "memory");
      const short* bs2 = sLds + (((t + 1) & 1) << 15);
#pragma unroll
      for (int rt = 0; rt < 4; ++rt) aA[rt] = *(const bf16x8*)(bs2 + aoff + rt * 512);
#pragma unroll
      for (int ct = 0; ct < 4; ++ct) bA[ct] = *(const bf16x8*)(bs2 + boff + ct * 512);
      if (t + 2 < KT) STAGE_Q(t + 2, 0);
      __builtin_amdgcn_sched_barrier(0);
    }
    __builtin_amdgcn_s_setprio(1);
#pragma unroll
    for (int rt = 0; rt < 4; ++rt)
#pragma unroll
      for (int ct = 0; ct < 4; ++ct)
        acc[4 + rt][ct] = __builtin_amdgcn_mfma_f32_16x16x32_bf16(aB[rt], bB[ct], acc[4 + rt][ct], 0, 0, 0);
    __builtin_amdgcn_s_setprio(0);
    __builtin_amdgcn_sched_barrier(0);
  }

  const int rowbase = bM + wr * 128;
  const int colbase = bN + wc * 64;

  if constexpr (MODE == 0) {
    // paired in_proj epilogue: even/odd ct frags = xi/g at the same phi.
    short* xid = (short*)out0;
    short* prd = (short*)out1;
#pragma unroll
    for (int cp = 0; cp < 2; ++cp) {
      const int newcolE = colbase + cp * 32 + m;
      const int phi = ((newcolE >> 5) << 4) | (newcolE & 15);   // 0..2047
      const float bxi = bias[phi];
      const float bg  = bias[DINNER + phi];
#pragma unroll
      for (int rt = 0; rt < 8; ++rt) {
        const size_t rowPan = ((size_t)(rowbase >> 4) + rt) << 8;
        const size_t base = ((rowPan + (phi >> 3)) << 7) + (phi & 7) + ((size_t)quad * 32);
#pragma unroll
        for (int reg = 0; reg < 4; ++reg) {
          const float xv = silu_f(acc[rt][2 * cp][reg] + bxi);
          const float gv = silu_f(acc[rt][2 * cp + 1][reg] + bg);
          xid[base + reg * 8] = f2bf(xv);
          prd[base + reg * 8] = f2bf(xv * gv);
        }
      }
    }
  } else {
    constexpr int N = NT * 256;
    short* dst = (short*)out0 + (size_t)z * MROWS * N;
#pragma unroll
    for (int rt = 0; rt < 8; ++rt)
#pragma unroll
      for (int ct = 0; ct < 4; ++ct) {
        const int col = colbase + ct * 16 + m;
#pragma unroll
        for (int reg = 0; reg < 4; ++reg) {
          const int r = rowbase + rt * 16 + quad * 4 + reg;
          dst[(size_t)r * N + col] = f2bf(acc[rt][ct][reg]);
        }
      }
  }
}

// ---------------- skinny xp GEMM: bx partials = xi @ W_xp (fp32) -------------
// 32KB LDS -> 4 blocks/CU = 4 waves/SIMD (why this 4-wave kernel is fine
// while R8's 96KB 1-wave/SIMD gemm128 was not).
__global__ __launch_bounds__(256) void xp_gemm(const short* __restrict__ xi,
                                               const short* __restrict__ Bxp,
                                               float* __restrict__ bxp) {
  __shared__ __attribute__((aligned(16))) short sA[2][4096];
  __shared__ __attribute__((aligned(16))) short sB[2][4096];
  const int tid = threadIdx.x, lane = tid & 63, w = tid >> 6;
  const int m = lane & 15, quad = lane >> 4;
  const int z = blockIdx.x >> 7;            // K-slice
  const int rb = (blockIdx.x & 127) * 64;   // row base
  const size_t PS = (size_t)2048 * 16;      // panel stride (shorts)
  const short* Ag = xi  + ((size_t)(rb >> 4) + w) * PS + (size_t)z * 1024 * 16 + lane * 8;
  const short* Bg = Bxp + (size_t)w * PS + (size_t)z * 1024 * 16 + lane * 8;
  floatx4 acc[4] = {};
  auto STAGE = [&](int t) {                 // 4 gld_lds per wave
    const size_t go = (size_t)t * 1024;
    short* da = sA[t & 1] + w * 1024;
    short* db = sB[t & 1] + w * 1024;
    gld_lds16(Ag + go, da); gld_lds16(Ag + go + 512, da + 512);
    gld_lds16(Bg + go, db); gld_lds16(Bg + go + 512, db + 512);
  };
  STAGE(0);
#pragma unroll 1
  for (int t = 0; t < 16; ++t) {
    __builtin_amdgcn_s_barrier();
    if (t + 1 < 16) {
      STAGE(t + 1);
      asm volatile("s_waitcnt vmcnt(4)" ::: "memory");
    } else {
      asm volatile("s_waitcnt vmcnt(0)" ::: "memory");
    }
    __builtin_amdgcn_s_barrier();
    const short* a0 = sA[t & 1] + w * 1024 + quad * 128 + m * 8;
    const short* b0 = sB[t & 1] + quad * 128 + m * 8;
#pragma unroll
    for (int kh = 0; kh < 2; ++kh) {
      bf16x8 a = *(const bf16x8*)(a0 + kh * 512);
#pragma unroll
      for (int ct = 0; ct < 4; ++ct) {
        bf16x8 b = *(const bf16x8*)(b0 + ct * 1024 + kh * 512);
        acc[ct] = __builtin_amdgcn_mfma_f32_16x16x32_bf16(a, b, acc[ct], 0, 0, 0);
      }
    }
  }
  float* dst = bxp + (size_t)z * MROWS * DSTATE;
#pragma unroll
  for (int ct = 0; ct < 4; ++ct)
#pragma unroll
    for (int reg = 0; reg < 4; ++reg)
      dst[(size_t)(rb + w * 16 + quad * 4 + reg) * DSTATE + ct * 16 + m] = acc[ct][reg];
}

// ---------------- split-K combine epilogues ----------------------------------
// G2: one wave per row; p[2][8192][1024] bf16 dt-partials -> md_sum
__global__ void g2_epilogue(const short* __restrict__ p, const float* __restrict__ b_dt,
                            float* __restrict__ md_sum) {
  const int row = blockIdx.x * 4 + (threadIdx.x >> 6);
  const int lane = threadIdx.x & 63;
  const size_t base0 = (size_t)row * 1024;
  const size_t base1 = base0 + (size_t)MROWS * 1024;
  short8 a0 = *(const short8*)(p + base0 + lane * 16);
  short8 a1 = *(const short8*)(p + base0 + lane * 16 + 8);
  short8 c0 = *(const short8*)(p + base1 + lane * 16);
  short8 c1 = *(const short8*)(p + base1 + lane * 16 + 8);
  float s = 0.f;
#pragma unroll
  for (int j = 0; j < 8; ++j) {
    s += softplus_f(bf2f(a0[j]) + bf2f(c0[j]) + b_dt[lane * 16 + j]);
    s += softplus_f(bf2f(a1[j]) + bf2f(c1[j]) + b_dt[lane * 16 + 8 + j]);
  }
  s += __shfl_xor(s, 1);  s += __shfl_xor(s, 2);  s += __shfl_xor(s, 4);
  s += __shfl_xor(s, 8);  s += __shfl_xor(s, 16); s += __shfl_xor(s, 32);
  if (lane == 0) md_sum[row] = s;
}

// G4: out = s_sum*(p0 + p1) + b_out + x*D   (fp32 row-major [8192,1024])
// s_sum applied here (linearity of matmul in A-rows). Batched 8 rows/block.
__global__ void g4_epilogue(const short* __restrict__ p, const float* __restrict__ b_out,
                            const float* __restrict__ x, const float* __restrict__ Dv,
                            const float* __restrict__ s_sum, float* __restrict__ out) {
  const int c = threadIdx.x * 4;
  const float bo0 = b_out[c + 0], bo1 = b_out[c + 1];
  const float bo2 = b_out[c + 2], bo3 = b_out[c + 3];
  const float d0 = Dv[c + 0], d1 = Dv[c + 1], d2 = Dv[c + 2], d3 = Dv[c + 3];
#pragma unroll
  for (int i = 0; i < 8; ++i) {
    const int r = blockIdx.x * 8 + i;
    const float s = s_sum[r];
    const size_t o = (size_t)r * DMODEL + c;
    short4 a0 = *(const short4*)(p + o);
    short4 a1 = *(const short4*)(p + (size_t)MROWS * DMODEL + o);
    float4 xv = *(const float4*)(x + o);
    float4 ov;
    ov.x = s * (bf2f(a0.x) + bf2f(a1.x)) + bo0 + xv.x * d0;
    ov.y = s * (bf2f(a0.y) + bf2f(a1.y)) + bo1 + xv.y * d1;
    ov.z = s * (bf2f(a0.z) + bf2f(a1.z)) + bo2 + xv.z * d2;
    ov.w = s * (bf2f(a0.w) + bf2f(a1.w)) + bo3 + xv.w * d3;
    *(float4*)(out + o) = ov;
  }
}

// ---------------- chunked selective scan (2 phases) --------------------------
// bx value = bxp[0][row][n] + bxp[1][row][n] + b_xp[n] (fp32 split-K partials)
__global__ void scan_phase1(const float* __restrict__ md_sum, const float* __restrict__ A_log,
                            const float* __restrict__ bxp, const float* __restrict__ b_xp,
                            float* __restrict__ chunk_prod, float* __restrict__ chunk_end) {
  const int n = threadIdx.x;                // 0..63 (state dim)
  const int c = blockIdx.x & (NCHUNK - 1);  // chunk
  const int b = blockIdx.x >> 6;            // batch
  const float An = -__expf(A_log[n]);
  const float bxn = b_xp[n];
  const float* bx0 = bxp;
  const float* bx1 = bxp + (size_t)MROWS * DSTATE;
  float prod = 1.f, st = 0.f;
  const int t0 = c * LCHUNK;
#pragma unroll 4
  for (int i = 0; i < LCHUNK; ++i) {
    const int t = t0 + i;
    const float md = md_sum[b * SEQ + t] * (1.f / DMODEL);
    const float a = __expf(An * md);
    const size_t idx = ((size_t)(b * SEQ + t)) * DSTATE + n;
    st = a * st + (bx0[idx] + bx1[idx] + bxn);
    prod *= a;
  }
  chunk_prod[(b * NCHUNK + c) * DSTATE + n] = prod;
  chunk_end [(b * NCHUNK + c) * DSTATE + n] = st;
}

// phase3: redo own chunk-prefix, recompute a=exp(An*md), emit s_sum
__global__ void scan_phase3(const float* __restrict__ md_sum, const float* __restrict__ A_log,
                            const float* __restrict__ bxp, const float* __restrict__ b_xp,
                            const float* __restrict__ chunk_prod,
                            const float* __restrict__ chunk_end,
                            float* __restrict__ s_sum) {
  const int n = threadIdx.x;
  const int c = blockIdx.x & (NCHUNK - 1);
  const int b = blockIdx.x >> 6;
  const float An = -__expf(A_log[n]);
  const float bxn = b_xp[n];
  const float* bx0 = bxp;
  const float* bx1 = bxp + (size_t)MROWS * DSTATE;
  float st = 0.f;
#pragma unroll 4
  for (int cc = 0; cc < c; ++cc) {
    const size_t idx = ((size_t)(b * NCHUNK + cc)) * DSTATE + n;
    st = chunk_prod[idx] * st + chunk_end[idx];
  }
  const int t0 = c * LCHUNK;
#pragma unroll 4
  for (int i = 0; i < LCHUNK; ++i) {
    const int t = t0 + i;
    const float md = md_sum[b * SEQ + t] * (1.f / DMODEL);
    const float a = __expf(An * md);
    const size_t idx = ((size_t)(b * SEQ + t)) * DSTATE + n;
    st = a * st + (bx0[idx] + bx1[idx] + bxn);
    float v = st;
    v += __shfl_xor(v, 32); v += __shfl_xor(v, 16); v += __shfl_xor(v, 8);
    v += __shfl_xor(v, 4);  v += __shfl_xor(v, 2);  v += __shfl_xor(v, 1);
    if (n == 0) s_sum[b * SEQ + t] = v;
  }
}

// ---------------- launch ------------------------------------------------------
extern "C" void kernel_launch(void* const* d_in, const int* in_sizes, int n_in,
                              void* d_out, int out_size, void* d_ws, size_t ws_size,
                              hipStream_t stream) {
  const float* x     = (const float*)d_in[0];
  const float* W_in  = (const float*)d_in[1];
  const float* b_in  = (const float*)d_in[2];
  const float* W_xp  = (const float*)d_in[3];
  const float* b_xp  = (const float*)d_in[4];
  const float* W_dt  = (const float*)d_in[5];
  const float* b_dt  = (const float*)d_in[6];
  const float* W_out = (const float*)d_in[7];
  const float* b_out = (const float*)d_in[8];
  const float* A_log = (const float*)d_in[9];
  const float* Dv    = (const float*)d_in[10];

  char* ws = (char*)d_ws;
  size_t off = 0;
  auto alloc = [&](size_t bytes) -> void* {
    void* p = (void*)(ws + off);
    off += (bytes + 255) & ~(size_t)255;
    return p;
  };
  short* x_bf    = (short*)alloc((size_t)MROWS * DMODEL * 2);
  short* Wt_in   = (short*)alloc((size_t)4096 * 1024 * 2);
  short* Bcat    = (short*)alloc((size_t)NCAT * DINNER * 2);
  short* Wt_out  = (short*)alloc((size_t)1024 * 2048 * 2);
  short* xi      = (short*)alloc((size_t)MROWS * DINNER * 2);   // also G4 partials
  short* prod    = (short*)alloc((size_t)MROWS * DINNER * 2);   // silu(xi)*silu(g)
  short* p2      = (short*)alloc((size_t)2 * MROWS * 1024 * 2); // G2 dt partials
  float* md_sum  = (float*)alloc((size_t)MROWS * 4);
  float* bxp     = (float*)alloc((size_t)2 * MROWS * DSTATE * 4); // xp partials
  float* cprod   = (float*)alloc((size_t)2 * NCHUNK * DSTATE * 4);
  float* cend    = (float*)alloc((size_t)2 * NCHUNK * DSTATE * 4);
  float* s_sum   = (float*)alloc((size_t)MROWS * 4);

  // fused pre-pass: x->bf16 (panel-staged) + all 4 weight transposes
  // (W_in transposed with the xi/g column-pairing remap; short8 writes)
  prepass_kernel<<<PP4, 256, 0, stream>>>(x, x_bf, W_in, Wt_in, W_dt, W_xp, Bcat, W_out, Wt_out);

  // GEMM1: in_proj, paired epilogue -> xi + prod (ymul folded in)
  gemm256<0, 1024, 1024, 16, 1><<<512, 512, 0, stream>>>(x_bf, Wt_in, b_in, xi, prod);
  // GEMM2-dt: 256^2 pipeline, split-K=2, N=1024 -> one clean round (256 blocks)
  gemm256<1, 2048, 1024, 4, 2><<<256, 512, 0, stream>>>(xi, Bcat, nullptr, p2, nullptr);
  // GEMM2-xp: skinny N=64, fp32 partials straight into bxp
  xp_gemm<<<256, 256, 0, stream>>>(xi, Bcat + (size_t)1024 * DINNER, bxp);
  // combine dt partials -> softplus rowsum
  g2_epilogue<<<MROWS / 4, 256, 0, stream>>>(p2, b_dt, md_sum);
  // selective scan (phase3 self-computes its chunk prefix)
  scan_phase1<<<2 * NCHUNK, DSTATE, 0, stream>>>(md_sum, A_log, bxp, b_xp, cprod, cend);
  scan_phase3<<<2 * NCHUNK, DSTATE, 0, stream>>>(md_sum, A_log, bxp, b_xp, cprod, cend, s_sum);
  // GEMM4: P = prod @ W_out, split-K=2 partials into xi's slot
  gemm256<1, 2048, 1024, 4, 2><<<256, 512, 0, stream>>>(prod, Wt_out, nullptr, xi, nullptr);
  // epilogue applies s_sum scale + b_out + x*D (8 rows/block)
  g4_epilogue<<<MROWS / 8, 256, 0, stream>>>(xi, b_out, x, Dv, s_sum, (float*)d_out);
}